// Round 9
// baseline (262.628 us; speedup 1.0000x reference)
//
#include <hip/hip_runtime.h>
#include <hip/hip_bf16.h>

// Problem constants (reference: N, E, K, F_IN, H = 50000, 640000, 3, 128, 128)
#define NN 50000
#define NE 640000
#define NP 196          // ceil(NN/256) zero blocks
#define CAP 64          // bucket capacity; deg~Poisson(12.8), P(deg>=64)~5e-27

typedef unsigned short ushort_t;
typedef unsigned int uint_t;
typedef __attribute__((ext_vector_type(8))) short bf16x8;   // 8 bf16 = 4 VGPRs
typedef __attribute__((ext_vector_type(4))) float f32x4;

__device__ __forceinline__ float b2f(ushort_t u) {
    union { uint_t u; float f; } v; v.u = ((uint_t)u) << 16; return v.f;
}
__device__ __forceinline__ ushort_t f2b(float f) {
    union { float f; uint_t u; } v; v.f = f;
    uint_t u = v.u;
    uint_t r = u + 0x7fffu + ((u >> 16) & 1u);   // round-nearest-even
    return (ushort_t)(r >> 16);
}
// fast transcendentals: v_exp + v_rcp (err ~1e-6, vs 4.9e-4 pipeline absmax)
__device__ __forceinline__ float fsig(float x)  { return __builtin_amdgcn_rcpf(1.0f + __expf(-x)); }
__device__ __forceinline__ float ftanh(float x) { return 1.0f - 2.0f * __builtin_amdgcn_rcpf(1.0f + __expf(2.0f * x)); }
// mode-aware scalar param load: mf=1 -> f32 array, mf=0 -> bf16 array
__device__ __forceinline__ float ldm(const void* p, int i, int mf) {
    return mf ? ((const float*)p)[i] : b2f(((const ushort_t*)p)[i]);
}

// ---- workspace layout (bytes), total 25.93 MB (known-good ceiling: 31.65 MB) ----
#define OFF_HB   0            // NN*128 bf16 (12,800,000)  dg[n]*h[n] pre-scaled
#define OFF_BSRC 12800000     // NN*CAP i32 (12,800,000)   fixed-capacity dst buckets
#define OFF_CNT  25600000     // NN i32     (200,000)      in-degree (bucket fill count)
#define OFF_WT   25800000     // 4*16384 bf16 (131,072)    Wi^T, Wc^T, Wo^T, gcn_w^T ([f][k])
#define OFF_COEF 25931072     // 641 f32    (2,564)
#define OFF_MODE 25933640     // i32
#define WS_REQ   25933648

__global__ void fb_k(ushort_t* __restrict__ out, int n) {   // ws too small: diagnostic zeros
    int i = blockIdx.x * blockDim.x + threadIdx.x;
    if (i < n) out[i] = 0;
}

// blocks 0..NP-1: zero cnt. block NP: dtype detect (f32-as-bf16 halves show
// huge exponents ~25% >= 0xC0; real bf16 N(0,1) never does).
__global__ void init_k(const ushort_t* __restrict__ x, int* __restrict__ cnt,
                       int* __restrict__ mode) {
    __shared__ int s[256];
    int b = blockIdx.x, t = threadIdx.x;
    if (b < NP) {
        int i = b * 256 + t;
        if (i < NN) cnt[i] = 0;
    } else {
        int bad = 0;
        for (int i = t; i < 4096; i += 256) {
            int e = (x[i] >> 7) & 0xFF;
            if (e >= 0xC0) bad++;
        }
        s[t] = bad; __syncthreads();
        for (int o = 128; o >= 1; o >>= 1) { if (t < o) s[t] += s[t + o]; __syncthreads(); }
        if (t == 0) mode[0] = (s[0] > 8) ? 1 : 0;   // 1 = f32 inputs, 0 = bf16
    }
}

// blocks 0..63: transpose W_x[0],W_x[2],W_x[3],gcn_w -> bf16 [f][k].
// block 64: fold biases (cheb(0)=theta_b), peephole w_c[2], relu->BN->linear tail.
__global__ void prep_k(const void* __restrict__ Wx, const void* __restrict__ gcnw,
                       const void* __restrict__ wc, const void* __restrict__ bb,
                       const void* __restrict__ thb,
                       const void* __restrict__ gam, const void* __restrict__ bet,
                       const void* __restrict__ mea, const void* __restrict__ var,
                       const void* __restrict__ linw, const void* __restrict__ linb,
                       const int* __restrict__ mode,
                       ushort_t* __restrict__ WT, float* __restrict__ coef) {
    __shared__ float red[128];
    int b = blockIdx.x, t = threadIdx.x;
    int mf = mode[0];
    if (b < 64) {
        int gid = b * 256 + t;
        int f = gid >> 7, k = gid & 127;
        const int srcoff[4] = { 0, 2 * 16384, 3 * 16384, 0 };
        #pragma unroll
        for (int m = 0; m < 4; m++) {
            const void* S = (m == 3) ? gcnw : Wx;
            WT[m * 16384 + gid] = f2b(ldm(S, srcoff[m] + k * 128 + f, mf));
        }
    } else {
        if (t < 128) {
            float rs = rsqrtf(ldm(var, t, mf) + 1e-5f);
            float ga = ldm(gam, t, mf);
            float lw = ldm(linw, t, mf);
            coef[t]       = ldm(thb, t, mf)           + ldm(bb, t, mf);            // bias_i
            coef[128 + t] = ldm(thb, 2 * 128 + t, mf) + ldm(bb, 2 * 128 + t, mf);  // bias_c
            coef[256 + t] = ldm(thb, 3 * 128 + t, mf) + ldm(bb, 3 * 128 + t, mf);  // bias_o
            coef[384 + t] = ldm(wc, 2 * 128 + t, mf);                              // w_c[2]
            coef[512 + t] = ga * rs * lw;                                          // s[f]
            red[t] = (ldm(bet, t, mf) - ldm(mea, t, mf) * ga * rs) * lw;
        }
        __syncthreads();
        for (int off = 64; off >= 1; off >>= 1) {
            if (t < off && t < 128) red[t] += red[t + off];
            __syncthreads();
        }
        if (t == 0) coef[640] = red[0] + ldm(linb, 0, mf);                         // C
    }
}

// single pass: count degree AND bucket edges (fixed CAP slots per destination)
__global__ void fill_k(const int* __restrict__ ei, int* __restrict__ cnt,
                       int* __restrict__ bsrc) {
    int e = blockIdx.x * blockDim.x + threadIdx.x;
    if (e < NE) {
        int s = ei[e], d = ei[NE + e];
        int slot = atomicAdd(&cnt[d], 1);
        if (slot < CAP) bsrc[d * CAP + slot] = s;
    }
}

// ---------------------------------------------------------------------------
// Fused gates + gcn GEMM -> hb = dg[n]*h[n] (bf16). One block = 4 waves =
// 64 nodes; wave w owns feature cols [32w,32w+32) for all rows (B-frags load
// once, reuse over 4 row tiles). dg computed inline from cnt.
// MFMA f32_16x16x32_bf16 layouts (HW-verified):
//   A: a[j]=A[m=lane&15][k=(lane>>4)*8+j];  B: b[j]=B[k=(lane>>4)*8+j][n=lane&15]
//   D: reg r -> row (lane>>4)*4+r, col lane&15
// ---------------------------------------------------------------------------
__launch_bounds__(256)
__global__ void gates_k(const void* __restrict__ x, const ushort_t* __restrict__ WT,
                        const float* __restrict__ coef, const int* __restrict__ cnt,
                        const int* __restrict__ mode, ushort_t* __restrict__ hb) {
    __shared__ ushort_t tile[64 * 136];   // +8 pad: row stride 272B
    __shared__ float ldsdg[64];
    int t = threadIdx.x;
    int base = blockIdx.x * 64;
    int mf = mode[0];

    if (t < 64) {
        int n = base + t;
        int c = (n < NN) ? cnt[n] : 0;
        if (c < 0) c = 0;
        ldsdg[t] = rsqrtf(1.0f + (float)c);
    }
    for (int i = 0; i < 4; i++) {
        int idx = (i * 256 + t) * 8;
        int row = idx >> 7, col = idx & 127;
        int n = base + row;
        bf16x8 v;
        if (n >= NN) {
            v = (bf16x8)0;
        } else if (mf == 0) {
            v = *(const bf16x8*)((const ushort_t*)x + n * 128 + col);
        } else {
            const float* xf = (const float*)x + n * 128 + col;
            float4 lo = *(const float4*)xf;
            float4 hi = *(const float4*)(xf + 4);
            v[0] = (short)f2b(lo.x); v[1] = (short)f2b(lo.y);
            v[2] = (short)f2b(lo.z); v[3] = (short)f2b(lo.w);
            v[4] = (short)f2b(hi.x); v[5] = (short)f2b(hi.y);
            v[6] = (short)f2b(hi.z); v[7] = (short)f2b(hi.w);
        }
        *(bf16x8*)&tile[row * 136 + col] = v;
    }
    __syncthreads();

    int lane = t & 63, wave = t >> 6;
    int m = lane & 15, quad = lane >> 4;

    // A-frags for all 4 row-tiles x 4 k-tiles (LDS, reused by both f-tiles)
    bf16x8 a[4][4];
    #pragma unroll
    for (int rt = 0; rt < 4; rt++)
        #pragma unroll
        for (int kt = 0; kt < 4; kt++)
            a[rt][kt] = *(const bf16x8*)&tile[(rt * 16 + m) * 136 + kt * 32 + quad * 8];
    __syncthreads();   // all x reads done before Hs overwrites tile

    const ushort_t* WTi = WT;
    const ushort_t* WTc = WT + 16384;
    const ushort_t* WTo = WT + 2 * 16384;

    #pragma unroll
    for (int ft = 0; ft < 2; ft++) {
        int f = wave * 32 + ft * 16 + m;
        // B-frags: loaded ONCE, reused across 4 row tiles
        bf16x8 bi[4], bc[4], bo[4];
        #pragma unroll
        for (int kt = 0; kt < 4; kt++) {
            int off = f * 128 + kt * 32 + quad * 8;
            bi[kt] = *(const bf16x8*)(WTi + off);
            bc[kt] = *(const bf16x8*)(WTc + off);
            bo[kt] = *(const bf16x8*)(WTo + off);
        }
        float bi_f = coef[f], bc_f = coef[128 + f], bo_f = coef[256 + f], w2 = coef[384 + f];
        #pragma unroll
        for (int rt = 0; rt < 4; rt++) {
            f32x4 ai = {0,0,0,0}, ac = {0,0,0,0}, ao = {0,0,0,0};
            #pragma unroll
            for (int kt = 0; kt < 4; kt++) {
                ai = __builtin_amdgcn_mfma_f32_16x16x32_bf16(a[rt][kt], bi[kt], ai, 0, 0, 0);
                ac = __builtin_amdgcn_mfma_f32_16x16x32_bf16(a[rt][kt], bc[kt], ac, 0, 0, 0);
                ao = __builtin_amdgcn_mfma_f32_16x16x32_bf16(a[rt][kt], bo[kt], ao, 0, 0, 0);
            }
            #pragma unroll
            for (int r = 0; r < 4; r++) {
                float I  = fsig(ai[r] + bi_f);
                float T  = ftanh(ac[r] + bc_f);
                float Cs = I * T;                       // F*C_prev = 0
                float O  = fsig(ao[r] + w2 * Cs + bo_f);
                float Hs = O * ftanh(Cs);
                tile[(rt * 16 + quad * 4 + r) * 136 + f] = f2b(Hs);
            }
        }
    }
    __syncthreads();   // Hs tile complete (col-partitioned across waves)

    const ushort_t* WTg = WT + 3 * 16384;
    bf16x8 ah[4][4];
    #pragma unroll
    for (int rt = 0; rt < 4; rt++)
        #pragma unroll
        for (int kt = 0; kt < 4; kt++)
            ah[rt][kt] = *(const bf16x8*)&tile[(rt * 16 + m) * 136 + kt * 32 + quad * 8];

    #pragma unroll
    for (int ft = 0; ft < 2; ft++) {
        int f = wave * 32 + ft * 16 + m;
        bf16x8 bg[4];
        #pragma unroll
        for (int kt = 0; kt < 4; kt++)
            bg[kt] = *(const bf16x8*)(WTg + f * 128 + kt * 32 + quad * 8);
        #pragma unroll
        for (int rt = 0; rt < 4; rt++) {
            f32x4 acc = {0,0,0,0};
            #pragma unroll
            for (int kt = 0; kt < 4; kt++)
                acc = __builtin_amdgcn_mfma_f32_16x16x32_bf16(ah[rt][kt], bg[kt], acc, 0, 0, 0);
            #pragma unroll
            for (int r = 0; r < 4; r++) {
                int n = base + rt * 16 + quad * 4 + r;
                if (n < NN)   // pre-scale by dg[n]: folds GCN coeffs into the row
                    hb[n * 128 + f] = f2b(ldsdg[rt * 16 + quad * 4 + r] * acc[r]);
            }
        }
    }
}

// ---------------------------------------------------------------------------
// Fused gather + self-loop + relu->BN->linear. One wave per destination.
// Quarter-wave per edge — 16 lanes x 16B = one 256B hb row; 2 edges/quarter
// in flight. R9 FIX: the gather loop is WAVE-UNIFORM (deg is wave-uniform);
// __shfl executes with all 64 lanes active (R8 had __shfl inside divergent
// per-quarter loops -> ds_bpermute from inactive lanes = undefined -> 2e-2
// absmax). Loads/accumulates are predicated, no cross-lane ops inside.
// g[d] = dg[d]*(sum_e hb[src] + hb[d]);  hb already dg[s]-scaled.
// ---------------------------------------------------------------------------
__launch_bounds__(256)
__global__ void gat_out_k(const ushort_t* __restrict__ hb, const int* __restrict__ cnt,
                          const int* __restrict__ bsrc,
                          const void* __restrict__ gcnb, const float* __restrict__ coef,
                          const int* __restrict__ mode, void* __restrict__ out) {
    int wid  = (blockIdx.x * blockDim.x + threadIdx.x) >> 6;
    int lane = threadIdx.x & 63;
    if (wid >= NN) return;
    int q = lane >> 4, sl = lane & 15;
    int c = cnt[wid]; if (c < 0) c = 0;
    int deg = (c < CAP) ? c : CAP;     // wave-uniform
    int myidx = (lane < deg) ? bsrc[wid * CAP + lane] : 0;

    float a0=0, a1=0, a2=0, a3=0, a4=0, a5=0, a6=0, a7=0;
    const ushort_t* hrow = hb + sl * 8;
    #define ACC(r)  do { \
        a0 += b2f((ushort_t)((r).x & 0xffffu)); a1 += b2f((ushort_t)((r).x >> 16)); \
        a2 += b2f((ushort_t)((r).y & 0xffffu)); a3 += b2f((ushort_t)((r).y >> 16)); \
        a4 += b2f((ushort_t)((r).z & 0xffffu)); a5 += b2f((ushort_t)((r).z >> 16)); \
        a6 += b2f((ushort_t)((r).w & 0xffffu)); a7 += b2f((ushort_t)((r).w >> 16)); } while (0)

    for (int jj = 0; jj < deg; jj += 8) {   // uniform trip count across wave
        int j0 = jj + q;                    // quarter q takes edges j0, j0+4
        int j1 = jj + q + 4;
        int s0 = __shfl(myidx, j0 & 63);    // all lanes active for the shfls
        int s1 = __shfl(myidx, j1 & 63);
        if (j0 < deg) { uint4 r0 = *(const uint4*)(hrow + s0 * 128); ACC(r0); }
        if (j1 < deg) { uint4 r1 = *(const uint4*)(hrow + s1 * 128); ACC(r1); }
    }
    if (q == 0) {                          // self term once (pre-combine)
        uint4 r = *(const uint4*)(hrow + wid * 128);
        ACC(r);
    }
    #undef ACC
    // combine quarters (lane l, l^16, l^32, l^48 hold same feats)
    a0 += __shfl_xor(a0, 16); a0 += __shfl_xor(a0, 32);
    a1 += __shfl_xor(a1, 16); a1 += __shfl_xor(a1, 32);
    a2 += __shfl_xor(a2, 16); a2 += __shfl_xor(a2, 32);
    a3 += __shfl_xor(a3, 16); a3 += __shfl_xor(a3, 32);
    a4 += __shfl_xor(a4, 16); a4 += __shfl_xor(a4, 32);
    a5 += __shfl_xor(a5, 16); a5 += __shfl_xor(a5, 32);
    a6 += __shfl_xor(a6, 16); a6 += __shfl_xor(a6, 32);
    a7 += __shfl_xor(a7, 16); a7 += __shfl_xor(a7, 32);

    int mf = mode[0];
    float d = rsqrtf(1.0f + (float)c);
    int fb = sl * 8;
    float v = 0.0f;
    float aa[8] = { a0, a1, a2, a3, a4, a5, a6, a7 };
    #pragma unroll
    for (int k = 0; k < 8; k++) {
        float g = d * aa[k] + ldm(gcnb, fb + k, mf);
        v += fmaxf(g, 0.0f) * coef[512 + fb + k];
    }
    #pragma unroll
    for (int o = 32; o >= 1; o >>= 1) v += __shfl_down(v, o);   // 4 quarter-copies -> 4x
    if (lane == 0) {
        float r = 0.25f * v + coef[640];
        if (mf) ((float*)out)[wid] = r;
        else    ((ushort_t*)out)[wid] = f2b(r);
    }
}

extern "C" void kernel_launch(void* const* d_in, const int* in_sizes, int n_in,
                              void* d_out, int out_size, void* d_ws, size_t ws_size,
                              hipStream_t stream) {
    if (ws_size < (size_t)WS_REQ) {   // diagnostic: finite 0.088 failure, not NaN
        fb_k<<<(out_size + 255) / 256, 256, 0, stream>>>((ushort_t*)d_out, out_size);
        return;
    }
    const void* x    = d_in[0];
    const int*  ei   = (const int*)d_in[1];
    // d_in[2] edge_weight: unused (ChebConv of zero state collapses to bias)
    const void* Wx   = d_in[3];
    const void* wc   = d_in[4];
    const void* bb   = d_in[5];
    // d_in[6] theta: unused
    const void* thb  = d_in[7];
    const void* gcnw = d_in[8];
    const void* gcnb = d_in[9];
    const void* gam  = d_in[10];
    const void* bet  = d_in[11];
    const void* mea  = d_in[12];
    const void* var  = d_in[13];
    const void* linw = d_in[14];
    const void* linb = d_in[15];

    char* ws = (char*)d_ws;
    ushort_t* hb   = (ushort_t*)(ws + OFF_HB);
    int*      bsrc = (int*)     (ws + OFF_BSRC);
    int*      cnt  = (int*)     (ws + OFF_CNT);
    ushort_t* WT   = (ushort_t*)(ws + OFF_WT);
    float*    coef = (float*)   (ws + OFF_COEF);
    int*      mode = (int*)     (ws + OFF_MODE);

    init_k<<<NP + 1, 256, 0, stream>>>((const ushort_t*)x, cnt, mode);
    prep_k<<<65, 256, 0, stream>>>(Wx, gcnw, wc, bb, thb, gam, bet, mea, var, linw, linb, mode, WT, coef);
    fill_k<<<(NE + 255) / 256, 256, 0, stream>>>(ei, cnt, bsrc);
    gates_k<<<(NN + 63) / 64, 256, 0, stream>>>(x, WT, coef, cnt, mode, hb);
    gat_out_k<<<(NN * 64 + 255) / 256, 256, 0, stream>>>(hb, cnt, bsrc, gcnb, coef, mode, d_out);
}

// Round 10
// 204.793 us; speedup vs baseline: 1.2824x; 1.2824x over previous
//
#include <hip/hip_runtime.h>
#include <hip/hip_bf16.h>

// Problem constants (reference: N, E, K, F_IN, H = 50000, 640000, 3, 128, 128)
#define NN 50000
#define NE 640000
#define NP 196          // ceil(NN/256) zero blocks
#define CAP 64          // bucket capacity; deg~Poisson(12.8), P(deg>=64)~5e-27

typedef unsigned short ushort_t;
typedef unsigned int uint_t;
typedef __attribute__((ext_vector_type(8))) short bf16x8;   // 8 bf16 = 4 VGPRs
typedef __attribute__((ext_vector_type(4))) float f32x4;

__device__ __forceinline__ float b2f(ushort_t u) {
    union { uint_t u; float f; } v; v.u = ((uint_t)u) << 16; return v.f;
}
__device__ __forceinline__ ushort_t f2b(float f) {
    union { float f; uint_t u; } v; v.f = f;
    uint_t u = v.u;
    uint_t r = u + 0x7fffu + ((u >> 16) & 1u);   // round-nearest-even
    return (ushort_t)(r >> 16);
}
// fast transcendentals: v_exp + v_rcp (err ~1e-6, vs 4.9e-4 pipeline absmax)
__device__ __forceinline__ float fsig(float x)  { return __builtin_amdgcn_rcpf(1.0f + __expf(-x)); }
__device__ __forceinline__ float ftanh(float x) { return 1.0f - 2.0f * __builtin_amdgcn_rcpf(1.0f + __expf(2.0f * x)); }
// mode-aware scalar param load: mf=1 -> f32 array, mf=0 -> bf16 array
__device__ __forceinline__ float ldm(const void* p, int i, int mf) {
    return mf ? ((const float*)p)[i] : b2f(((const ushort_t*)p)[i]);
}

// ---- workspace layout (bytes), total 25.93 MB (known-good ceiling: 31.65 MB) ----
#define OFF_HB   0            // NN*128 bf16 (12,800,000)  dg[n]*h[n] pre-scaled
#define OFF_BSRC 12800000     // NN*CAP i32 (12,800,000)   fixed-capacity dst buckets
#define OFF_CNT  25600000     // NN i32     (200,000)      in-degree (bucket fill count)
#define OFF_WT   25800000     // 4*16384 bf16 (131,072)    Wi^T, Wc^T, Wo^T, gcn_w^T ([f][k])
#define OFF_COEF 25931072     // 641 f32    (2,564)
#define OFF_MODE 25933640     // i32
#define WS_REQ   25933648

__global__ void fb_k(ushort_t* __restrict__ out, int n) {   // ws too small: diagnostic zeros
    int i = blockIdx.x * blockDim.x + threadIdx.x;
    if (i < n) out[i] = 0;
}

// blocks 0..NP-1: zero cnt. block NP: dtype detect (f32-as-bf16 halves show
// huge exponents ~25% >= 0xC0; real bf16 N(0,1) never does).
__global__ void init_k(const ushort_t* __restrict__ x, int* __restrict__ cnt,
                       int* __restrict__ mode) {
    __shared__ int s[256];
    int b = blockIdx.x, t = threadIdx.x;
    if (b < NP) {
        int i = b * 256 + t;
        if (i < NN) cnt[i] = 0;
    } else {
        int bad = 0;
        for (int i = t; i < 4096; i += 256) {
            int e = (x[i] >> 7) & 0xFF;
            if (e >= 0xC0) bad++;
        }
        s[t] = bad; __syncthreads();
        for (int o = 128; o >= 1; o >>= 1) { if (t < o) s[t] += s[t + o]; __syncthreads(); }
        if (t == 0) mode[0] = (s[0] > 8) ? 1 : 0;   // 1 = f32 inputs, 0 = bf16
    }
}

// blocks 0..63: transpose W_x[0],W_x[2],W_x[3],gcn_w -> bf16 [f][k].
// block 64: fold biases (cheb(0)=theta_b), peephole w_c[2], relu->BN->linear tail.
__global__ void prep_k(const void* __restrict__ Wx, const void* __restrict__ gcnw,
                       const void* __restrict__ wc, const void* __restrict__ bb,
                       const void* __restrict__ thb,
                       const void* __restrict__ gam, const void* __restrict__ bet,
                       const void* __restrict__ mea, const void* __restrict__ var,
                       const void* __restrict__ linw, const void* __restrict__ linb,
                       const int* __restrict__ mode,
                       ushort_t* __restrict__ WT, float* __restrict__ coef) {
    __shared__ float red[128];
    int b = blockIdx.x, t = threadIdx.x;
    int mf = mode[0];
    if (b < 64) {
        int gid = b * 256 + t;
        int f = gid >> 7, k = gid & 127;
        const int srcoff[4] = { 0, 2 * 16384, 3 * 16384, 0 };
        #pragma unroll
        for (int m = 0; m < 4; m++) {
            const void* S = (m == 3) ? gcnw : Wx;
            WT[m * 16384 + gid] = f2b(ldm(S, srcoff[m] + k * 128 + f, mf));
        }
    } else {
        if (t < 128) {
            float rs = rsqrtf(ldm(var, t, mf) + 1e-5f);
            float ga = ldm(gam, t, mf);
            float lw = ldm(linw, t, mf);
            coef[t]       = ldm(thb, t, mf)           + ldm(bb, t, mf);            // bias_i
            coef[128 + t] = ldm(thb, 2 * 128 + t, mf) + ldm(bb, 2 * 128 + t, mf);  // bias_c
            coef[256 + t] = ldm(thb, 3 * 128 + t, mf) + ldm(bb, 3 * 128 + t, mf);  // bias_o
            coef[384 + t] = ldm(wc, 2 * 128 + t, mf);                              // w_c[2]
            coef[512 + t] = ga * rs * lw;                                          // s[f]
            red[t] = (ldm(bet, t, mf) - ldm(mea, t, mf) * ga * rs) * lw;
        }
        __syncthreads();
        for (int off = 64; off >= 1; off >>= 1) {
            if (t < off && t < 128) red[t] += red[t + off];
            __syncthreads();
        }
        if (t == 0) coef[640] = red[0] + ldm(linb, 0, mf);                         // C
    }
}

// single pass: count degree AND bucket edges (fixed CAP slots per destination)
__global__ void fill_k(const int* __restrict__ ei, int* __restrict__ cnt,
                       int* __restrict__ bsrc) {
    int e = blockIdx.x * blockDim.x + threadIdx.x;
    if (e < NE) {
        int s = ei[e], d = ei[NE + e];
        int slot = atomicAdd(&cnt[d], 1);
        if (slot < CAP) bsrc[d * CAP + slot] = s;
    }
}

// ---------------------------------------------------------------------------
// Fused gates + gcn GEMM -> hb = dg[n]*h[n] (bf16). One block = 4 waves =
// 64 nodes; wave w owns feature cols [32w,32w+32) for all rows (B-frags load
// once, reuse over 4 row tiles). dg computed inline from cnt.
// MFMA f32_16x16x32_bf16 layouts (HW-verified):
//   A: a[j]=A[m=lane&15][k=(lane>>4)*8+j];  B: b[j]=B[k=(lane>>4)*8+j][n=lane&15]
//   D: reg r -> row (lane>>4)*4+r, col lane&15
// ---------------------------------------------------------------------------
__launch_bounds__(256)
__global__ void gates_k(const void* __restrict__ x, const ushort_t* __restrict__ WT,
                        const float* __restrict__ coef, const int* __restrict__ cnt,
                        const int* __restrict__ mode, ushort_t* __restrict__ hb) {
    __shared__ ushort_t tile[64 * 136];   // +8 pad: row stride 272B
    __shared__ float ldsdg[64];
    int t = threadIdx.x;
    int base = blockIdx.x * 64;
    int mf = mode[0];

    if (t < 64) {
        int n = base + t;
        int c = (n < NN) ? cnt[n] : 0;
        if (c < 0) c = 0;
        ldsdg[t] = rsqrtf(1.0f + (float)c);
    }
    for (int i = 0; i < 4; i++) {
        int idx = (i * 256 + t) * 8;
        int row = idx >> 7, col = idx & 127;
        int n = base + row;
        bf16x8 v;
        if (n >= NN) {
            v = (bf16x8)0;
        } else if (mf == 0) {
            v = *(const bf16x8*)((const ushort_t*)x + n * 128 + col);
        } else {
            const float* xf = (const float*)x + n * 128 + col;
            float4 lo = *(const float4*)xf;
            float4 hi = *(const float4*)(xf + 4);
            v[0] = (short)f2b(lo.x); v[1] = (short)f2b(lo.y);
            v[2] = (short)f2b(lo.z); v[3] = (short)f2b(lo.w);
            v[4] = (short)f2b(hi.x); v[5] = (short)f2b(hi.y);
            v[6] = (short)f2b(hi.z); v[7] = (short)f2b(hi.w);
        }
        *(bf16x8*)&tile[row * 136 + col] = v;
    }
    __syncthreads();

    int lane = t & 63, wave = t >> 6;
    int m = lane & 15, quad = lane >> 4;

    // A-frags for all 4 row-tiles x 4 k-tiles (LDS, reused by both f-tiles)
    bf16x8 a[4][4];
    #pragma unroll
    for (int rt = 0; rt < 4; rt++)
        #pragma unroll
        for (int kt = 0; kt < 4; kt++)
            a[rt][kt] = *(const bf16x8*)&tile[(rt * 16 + m) * 136 + kt * 32 + quad * 8];
    __syncthreads();   // all x reads done before Hs overwrites tile

    const ushort_t* WTi = WT;
    const ushort_t* WTc = WT + 16384;
    const ushort_t* WTo = WT + 2 * 16384;

    #pragma unroll
    for (int ft = 0; ft < 2; ft++) {
        int f = wave * 32 + ft * 16 + m;
        // B-frags: loaded ONCE, reused across 4 row tiles
        bf16x8 bi[4], bc[4], bo[4];
        #pragma unroll
        for (int kt = 0; kt < 4; kt++) {
            int off = f * 128 + kt * 32 + quad * 8;
            bi[kt] = *(const bf16x8*)(WTi + off);
            bc[kt] = *(const bf16x8*)(WTc + off);
            bo[kt] = *(const bf16x8*)(WTo + off);
        }
        float bi_f = coef[f], bc_f = coef[128 + f], bo_f = coef[256 + f], w2 = coef[384 + f];
        #pragma unroll
        for (int rt = 0; rt < 4; rt++) {
            f32x4 ai = {0,0,0,0}, ac = {0,0,0,0}, ao = {0,0,0,0};
            #pragma unroll
            for (int kt = 0; kt < 4; kt++) {
                ai = __builtin_amdgcn_mfma_f32_16x16x32_bf16(a[rt][kt], bi[kt], ai, 0, 0, 0);
                ac = __builtin_amdgcn_mfma_f32_16x16x32_bf16(a[rt][kt], bc[kt], ac, 0, 0, 0);
                ao = __builtin_amdgcn_mfma_f32_16x16x32_bf16(a[rt][kt], bo[kt], ao, 0, 0, 0);
            }
            #pragma unroll
            for (int r = 0; r < 4; r++) {
                float I  = fsig(ai[r] + bi_f);
                float T  = ftanh(ac[r] + bc_f);
                float Cs = I * T;                       // F*C_prev = 0
                float O  = fsig(ao[r] + w2 * Cs + bo_f);
                float Hs = O * ftanh(Cs);
                tile[(rt * 16 + quad * 4 + r) * 136 + f] = f2b(Hs);
            }
        }
    }
    __syncthreads();   // Hs tile complete (col-partitioned across waves)

    const ushort_t* WTg = WT + 3 * 16384;
    bf16x8 ah[4][4];
    #pragma unroll
    for (int rt = 0; rt < 4; rt++)
        #pragma unroll
        for (int kt = 0; kt < 4; kt++)
            ah[rt][kt] = *(const bf16x8*)&tile[(rt * 16 + m) * 136 + kt * 32 + quad * 8];

    #pragma unroll
    for (int ft = 0; ft < 2; ft++) {
        int f = wave * 32 + ft * 16 + m;
        bf16x8 bg[4];
        #pragma unroll
        for (int kt = 0; kt < 4; kt++)
            bg[kt] = *(const bf16x8*)(WTg + f * 128 + kt * 32 + quad * 8);
        #pragma unroll
        for (int rt = 0; rt < 4; rt++) {
            f32x4 acc = {0,0,0,0};
            #pragma unroll
            for (int kt = 0; kt < 4; kt++)
                acc = __builtin_amdgcn_mfma_f32_16x16x32_bf16(ah[rt][kt], bg[kt], acc, 0, 0, 0);
            #pragma unroll
            for (int r = 0; r < 4; r++) {
                int n = base + rt * 16 + quad * 4 + r;
                if (n < NN)   // pre-scale by dg[n]: folds GCN coeffs into the row
                    hb[n * 128 + f] = f2b(ldsdg[rt * 16 + quad * 4 + r] * acc[r]);
            }
        }
    }
}

// ---------------------------------------------------------------------------
// Fused gather + self-loop + relu->BN->linear. One wave per destination.
// R10: revert to R7's measured-good half-wave gather (R9's quarter-wave+shfl
// chained ds_bpermute before each dependent load -> BW halved, 104us). Lanes
// 0-31 take edge j, lanes 32-63 edge j+1; 4B/lane row slice; bsrc loads are
// per-half broadcasts (no cross-lane ops in the loop). Buckets are
// CAP-strided; deg from cnt inline.
// g[d] = dg[d]*(sum_e hb[src] + hb[d]);  hb already dg[s]-scaled.
// ---------------------------------------------------------------------------
__launch_bounds__(256)
__global__ void gat_out_k(const ushort_t* __restrict__ hb, const int* __restrict__ cnt,
                          const int* __restrict__ bsrc,
                          const void* __restrict__ gcnb, const float* __restrict__ coef,
                          const int* __restrict__ mode, void* __restrict__ out) {
    int wid  = (blockIdx.x * blockDim.x + threadIdx.x) >> 6;
    int lane = threadIdx.x & 63;
    if (wid >= NN) return;
    int half = lane >> 5, sl = lane & 31;
    int c = cnt[wid]; if (c < 0) c = 0;
    int deg = (c < CAP) ? c : CAP;
    const int* brow = bsrc + wid * CAP;

    float a0 = 0.0f, a1 = 0.0f, a2 = 0.0f, a3 = 0.0f;
    int j = half;
    for (; j + 2 < deg; j += 4) {          // 2 edges per half-wave in flight
        int s0 = brow[j], s1 = brow[j + 2];
        uint2 r0 = *(const uint2*)(hb + s0 * 128 + sl * 4);
        uint2 r1 = *(const uint2*)(hb + s1 * 128 + sl * 4);
        a0 += b2f((ushort_t)(r0.x & 0xffffu)) + b2f((ushort_t)(r1.x & 0xffffu));
        a1 += b2f((ushort_t)(r0.x >> 16))     + b2f((ushort_t)(r1.x >> 16));
        a2 += b2f((ushort_t)(r0.y & 0xffffu)) + b2f((ushort_t)(r1.y & 0xffffu));
        a3 += b2f((ushort_t)(r0.y >> 16))     + b2f((ushort_t)(r1.y >> 16));
    }
    if (j < deg) {
        int s = brow[j];
        uint2 r = *(const uint2*)(hb + s * 128 + sl * 4);
        a0 += b2f((ushort_t)(r.x & 0xffffu));
        a1 += b2f((ushort_t)(r.x >> 16));
        a2 += b2f((ushort_t)(r.y & 0xffffu));
        a3 += b2f((ushort_t)(r.y >> 16));
    }
    if (half == 0) {                       // self term once (pre-combine)
        uint2 r = *(const uint2*)(hb + wid * 128 + sl * 4);
        a0 += b2f((ushort_t)(r.x & 0xffffu));
        a1 += b2f((ushort_t)(r.x >> 16));
        a2 += b2f((ushort_t)(r.y & 0xffffu));
        a3 += b2f((ushort_t)(r.y >> 16));
    }
    // combine halves (same feats in lane l and l^32)
    a0 += __shfl_xor(a0, 32); a1 += __shfl_xor(a1, 32);
    a2 += __shfl_xor(a2, 32); a3 += __shfl_xor(a3, 32);
    int mf = mode[0];
    float d = rsqrtf(1.0f + (float)c);
    int fb = sl * 4;
    float g0 = d * a0 + ldm(gcnb, fb,     mf);
    float g1 = d * a1 + ldm(gcnb, fb + 1, mf);
    float g2 = d * a2 + ldm(gcnb, fb + 2, mf);
    float g3 = d * a3 + ldm(gcnb, fb + 3, mf);
    float v = fmaxf(g0, 0.0f) * coef[512 + fb]
            + fmaxf(g1, 0.0f) * coef[512 + fb + 1]
            + fmaxf(g2, 0.0f) * coef[512 + fb + 2]
            + fmaxf(g3, 0.0f) * coef[512 + fb + 3];
    #pragma unroll
    for (int o = 32; o >= 1; o >>= 1) v += __shfl_down(v, o);   // sums both halves = 2x
    if (lane == 0) {
        float r = 0.5f * v + coef[640];
        if (mf) ((float*)out)[wid] = r;
        else    ((ushort_t*)out)[wid] = f2b(r);
    }
}

extern "C" void kernel_launch(void* const* d_in, const int* in_sizes, int n_in,
                              void* d_out, int out_size, void* d_ws, size_t ws_size,
                              hipStream_t stream) {
    if (ws_size < (size_t)WS_REQ) {   // diagnostic: finite 0.088 failure, not NaN
        fb_k<<<(out_size + 255) / 256, 256, 0, stream>>>((ushort_t*)d_out, out_size);
        return;
    }
    const void* x    = d_in[0];
    const int*  ei   = (const int*)d_in[1];
    // d_in[2] edge_weight: unused (ChebConv of zero state collapses to bias)
    const void* Wx   = d_in[3];
    const void* wc   = d_in[4];
    const void* bb   = d_in[5];
    // d_in[6] theta: unused
    const void* thb  = d_in[7];
    const void* gcnw = d_in[8];
    const void* gcnb = d_in[9];
    const void* gam  = d_in[10];
    const void* bet  = d_in[11];
    const void* mea  = d_in[12];
    const void* var  = d_in[13];
    const void* linw = d_in[14];
    const void* linb = d_in[15];

    char* ws = (char*)d_ws;
    ushort_t* hb   = (ushort_t*)(ws + OFF_HB);
    int*      bsrc = (int*)     (ws + OFF_BSRC);
    int*      cnt  = (int*)     (ws + OFF_CNT);
    ushort_t* WT   = (ushort_t*)(ws + OFF_WT);
    float*    coef = (float*)   (ws + OFF_COEF);
    int*      mode = (int*)     (ws + OFF_MODE);

    init_k<<<NP + 1, 256, 0, stream>>>((const ushort_t*)x, cnt, mode);
    prep_k<<<65, 256, 0, stream>>>(Wx, gcnw, wc, bb, thb, gam, bet, mea, var, linw, linb, mode, WT, coef);
    fill_k<<<(NE + 255) / 256, 256, 0, stream>>>(ei, cnt, bsrc);
    gates_k<<<(NN + 63) / 64, 256, 0, stream>>>(x, WT, coef, cnt, mode, hb);
    gat_out_k<<<(NN * 64 + 255) / 256, 256, 0, stream>>>(hb, cnt, bsrc, gcnb, coef, mode, d_out);
}

// Round 11
// 201.136 us; speedup vs baseline: 1.3057x; 1.0182x over previous
//
#include <hip/hip_runtime.h>
#include <hip/hip_bf16.h>

// Problem constants (reference: N, E, K, F_IN, H = 50000, 640000, 3, 128, 128)
#define NN 50000
#define NE 640000
#define NP 196          // ceil(NN/256) zero blocks
#define CAP 64          // bucket capacity; deg~Poisson(12.8), P(deg>=64)~5e-27

typedef unsigned short ushort_t;
typedef unsigned int uint_t;
typedef __attribute__((ext_vector_type(8))) short bf16x8;   // 8 bf16 = 4 VGPRs
typedef __attribute__((ext_vector_type(4))) float f32x4;

__device__ __forceinline__ float b2f(ushort_t u) {
    union { uint_t u; float f; } v; v.u = ((uint_t)u) << 16; return v.f;
}
__device__ __forceinline__ ushort_t f2b(float f) {
    union { float f; uint_t u; } v; v.f = f;
    uint_t u = v.u;
    uint_t r = u + 0x7fffu + ((u >> 16) & 1u);   // round-nearest-even
    return (ushort_t)(r >> 16);
}
// fast transcendentals: v_exp + v_rcp (err ~1e-6, vs 4.9e-4 pipeline absmax)
__device__ __forceinline__ float fsig(float x)  { return __builtin_amdgcn_rcpf(1.0f + __expf(-x)); }
__device__ __forceinline__ float ftanh(float x) { return 1.0f - 2.0f * __builtin_amdgcn_rcpf(1.0f + __expf(2.0f * x)); }
// mode-aware scalar param load: mf=1 -> f32 array, mf=0 -> bf16 array
__device__ __forceinline__ float ldm(const void* p, int i, int mf) {
    return mf ? ((const float*)p)[i] : b2f(((const ushort_t*)p)[i]);
}

// ---- workspace layout (bytes), total 25.93 MB (known-good ceiling: 31.65 MB) ----
#define OFF_HB   0            // NN*128 bf16 (12,800,000)  dg[n]*h[n] pre-scaled
#define OFF_BSRC 12800000     // NN*CAP i32 (12,800,000)   fixed-capacity dst buckets
#define OFF_CNT  25600000     // NN i32     (200,000)      in-degree (bucket fill count)
#define OFF_WT   25800000     // 4*16384 bf16 (131,072)    Wi^T, Wc^T, Wo^T, gcn_w^T ([f][k])
#define OFF_COEF 25931072     // 641 f32    (2,564)
#define OFF_MODE 25933640     // i32
#define WS_REQ   25933648

__global__ void fb_k(ushort_t* __restrict__ out, int n) {   // ws too small: diagnostic zeros
    int i = blockIdx.x * blockDim.x + threadIdx.x;
    if (i < n) out[i] = 0;
}

// blocks 0..NP-1: zero cnt. block NP: dtype detect (f32-as-bf16 halves show
// huge exponents ~25% >= 0xC0; real bf16 N(0,1) never does).
__global__ void init_k(const ushort_t* __restrict__ x, int* __restrict__ cnt,
                       int* __restrict__ mode) {
    __shared__ int s[256];
    int b = blockIdx.x, t = threadIdx.x;
    if (b < NP) {
        int i = b * 256 + t;
        if (i < NN) cnt[i] = 0;
    } else {
        int bad = 0;
        for (int i = t; i < 4096; i += 256) {
            int e = (x[i] >> 7) & 0xFF;
            if (e >= 0xC0) bad++;
        }
        s[t] = bad; __syncthreads();
        for (int o = 128; o >= 1; o >>= 1) { if (t < o) s[t] += s[t + o]; __syncthreads(); }
        if (t == 0) mode[0] = (s[0] > 8) ? 1 : 0;   // 1 = f32 inputs, 0 = bf16
    }
}

// blocks 0..63: transpose W_x[0],W_x[2],W_x[3],gcn_w -> bf16 [f][k].
// block 64: fold biases (cheb(0)=theta_b), peephole w_c[2], relu->BN->linear tail.
__global__ void prep_k(const void* __restrict__ Wx, const void* __restrict__ gcnw,
                       const void* __restrict__ wc, const void* __restrict__ bb,
                       const void* __restrict__ thb,
                       const void* __restrict__ gam, const void* __restrict__ bet,
                       const void* __restrict__ mea, const void* __restrict__ var,
                       const void* __restrict__ linw, const void* __restrict__ linb,
                       const int* __restrict__ mode,
                       ushort_t* __restrict__ WT, float* __restrict__ coef) {
    __shared__ float red[128];
    int b = blockIdx.x, t = threadIdx.x;
    int mf = mode[0];
    if (b < 64) {
        int gid = b * 256 + t;
        int f = gid >> 7, k = gid & 127;
        const int srcoff[4] = { 0, 2 * 16384, 3 * 16384, 0 };
        #pragma unroll
        for (int m = 0; m < 4; m++) {
            const void* S = (m == 3) ? gcnw : Wx;
            WT[m * 16384 + gid] = f2b(ldm(S, srcoff[m] + k * 128 + f, mf));
        }
    } else {
        if (t < 128) {
            float rs = rsqrtf(ldm(var, t, mf) + 1e-5f);
            float ga = ldm(gam, t, mf);
            float lw = ldm(linw, t, mf);
            coef[t]       = ldm(thb, t, mf)           + ldm(bb, t, mf);            // bias_i
            coef[128 + t] = ldm(thb, 2 * 128 + t, mf) + ldm(bb, 2 * 128 + t, mf);  // bias_c
            coef[256 + t] = ldm(thb, 3 * 128 + t, mf) + ldm(bb, 3 * 128 + t, mf);  // bias_o
            coef[384 + t] = ldm(wc, 2 * 128 + t, mf);                              // w_c[2]
            coef[512 + t] = ga * rs * lw;                                          // s[f]
            red[t] = (ldm(bet, t, mf) - ldm(mea, t, mf) * ga * rs) * lw;
        }
        __syncthreads();
        for (int off = 64; off >= 1; off >>= 1) {
            if (t < off && t < 128) red[t] += red[t + off];
            __syncthreads();
        }
        if (t == 0) coef[640] = red[0] + ldm(linb, 0, mf);                         // C
    }
}

// single pass: count degree AND bucket edges (fixed CAP slots per destination).
// R11: 4 edges per thread via int4 loads — R10's 1-edge/thread was a
// dependent atomic->store chain with nothing else in flight (49.5us,
// VALUBusy 0.4%); 4 independent atomics pipeline the latency.
__global__ void fill_k(const int* __restrict__ ei, int* __restrict__ cnt,
                       int* __restrict__ bsrc) {
    int tid = blockIdx.x * blockDim.x + threadIdx.x;   // NE/4 threads
    if (tid >= NE / 4) return;
    int4 s4 = ((const int4*)ei)[tid];
    int4 d4 = ((const int4*)(ei + NE))[tid];
    int p0 = atomicAdd(&cnt[d4.x], 1);
    int p1 = atomicAdd(&cnt[d4.y], 1);
    int p2 = atomicAdd(&cnt[d4.z], 1);
    int p3 = atomicAdd(&cnt[d4.w], 1);
    if (p0 < CAP) bsrc[d4.x * CAP + p0] = s4.x;
    if (p1 < CAP) bsrc[d4.y * CAP + p1] = s4.y;
    if (p2 < CAP) bsrc[d4.z * CAP + p2] = s4.z;
    if (p3 < CAP) bsrc[d4.w * CAP + p3] = s4.w;
}

// ---------------------------------------------------------------------------
// Fused gates + gcn GEMM -> hb = dg[n]*h[n] (bf16). One block = 4 waves =
// 64 nodes; wave w owns feature cols [32w,32w+32) for all rows (B-frags load
// once, reuse over 4 row tiles). dg computed inline from cnt.
// MFMA f32_16x16x32_bf16 layouts (HW-verified):
//   A: a[j]=A[m=lane&15][k=(lane>>4)*8+j];  B: b[j]=B[k=(lane>>4)*8+j][n=lane&15]
//   D: reg r -> row (lane>>4)*4+r, col lane&15
// ---------------------------------------------------------------------------
__launch_bounds__(256)
__global__ void gates_k(const void* __restrict__ x, const ushort_t* __restrict__ WT,
                        const float* __restrict__ coef, const int* __restrict__ cnt,
                        const int* __restrict__ mode, ushort_t* __restrict__ hb) {
    __shared__ ushort_t tile[64 * 136];   // +8 pad: row stride 272B
    __shared__ float ldsdg[64];
    int t = threadIdx.x;
    int base = blockIdx.x * 64;
    int mf = mode[0];

    if (t < 64) {
        int n = base + t;
        int c = (n < NN) ? cnt[n] : 0;
        if (c < 0) c = 0;
        ldsdg[t] = rsqrtf(1.0f + (float)c);
    }
    for (int i = 0; i < 4; i++) {
        int idx = (i * 256 + t) * 8;
        int row = idx >> 7, col = idx & 127;
        int n = base + row;
        bf16x8 v;
        if (n >= NN) {
            v = (bf16x8)0;
        } else if (mf == 0) {
            v = *(const bf16x8*)((const ushort_t*)x + n * 128 + col);
        } else {
            const float* xf = (const float*)x + n * 128 + col;
            float4 lo = *(const float4*)xf;
            float4 hi = *(const float4*)(xf + 4);
            v[0] = (short)f2b(lo.x); v[1] = (short)f2b(lo.y);
            v[2] = (short)f2b(lo.z); v[3] = (short)f2b(lo.w);
            v[4] = (short)f2b(hi.x); v[5] = (short)f2b(hi.y);
            v[6] = (short)f2b(hi.z); v[7] = (short)f2b(hi.w);
        }
        *(bf16x8*)&tile[row * 136 + col] = v;
    }
    __syncthreads();

    int lane = t & 63, wave = t >> 6;
    int m = lane & 15, quad = lane >> 4;

    // A-frags for all 4 row-tiles x 4 k-tiles (LDS, reused by both f-tiles)
    bf16x8 a[4][4];
    #pragma unroll
    for (int rt = 0; rt < 4; rt++)
        #pragma unroll
        for (int kt = 0; kt < 4; kt++)
            a[rt][kt] = *(const bf16x8*)&tile[(rt * 16 + m) * 136 + kt * 32 + quad * 8];
    __syncthreads();   // all x reads done before Hs overwrites tile

    const ushort_t* WTi = WT;
    const ushort_t* WTc = WT + 16384;
    const ushort_t* WTo = WT + 2 * 16384;

    #pragma unroll
    for (int ft = 0; ft < 2; ft++) {
        int f = wave * 32 + ft * 16 + m;
        // B-frags: loaded ONCE, reused across 4 row tiles
        bf16x8 bi[4], bc[4], bo[4];
        #pragma unroll
        for (int kt = 0; kt < 4; kt++) {
            int off = f * 128 + kt * 32 + quad * 8;
            bi[kt] = *(const bf16x8*)(WTi + off);
            bc[kt] = *(const bf16x8*)(WTc + off);
            bo[kt] = *(const bf16x8*)(WTo + off);
        }
        float bi_f = coef[f], bc_f = coef[128 + f], bo_f = coef[256 + f], w2 = coef[384 + f];
        #pragma unroll
        for (int rt = 0; rt < 4; rt++) {
            f32x4 ai = {0,0,0,0}, ac = {0,0,0,0}, ao = {0,0,0,0};
            #pragma unroll
            for (int kt = 0; kt < 4; kt++) {
                ai = __builtin_amdgcn_mfma_f32_16x16x32_bf16(a[rt][kt], bi[kt], ai, 0, 0, 0);
                ac = __builtin_amdgcn_mfma_f32_16x16x32_bf16(a[rt][kt], bc[kt], ac, 0, 0, 0);
                ao = __builtin_amdgcn_mfma_f32_16x16x32_bf16(a[rt][kt], bo[kt], ao, 0, 0, 0);
            }
            #pragma unroll
            for (int r = 0; r < 4; r++) {
                float I  = fsig(ai[r] + bi_f);
                float T  = ftanh(ac[r] + bc_f);
                float Cs = I * T;                       // F*C_prev = 0
                float O  = fsig(ao[r] + w2 * Cs + bo_f);
                float Hs = O * ftanh(Cs);
                tile[(rt * 16 + quad * 4 + r) * 136 + f] = f2b(Hs);
            }
        }
    }
    __syncthreads();   // Hs tile complete (col-partitioned across waves)

    const ushort_t* WTg = WT + 3 * 16384;
    bf16x8 ah[4][4];
    #pragma unroll
    for (int rt = 0; rt < 4; rt++)
        #pragma unroll
        for (int kt = 0; kt < 4; kt++)
            ah[rt][kt] = *(const bf16x8*)&tile[(rt * 16 + m) * 136 + kt * 32 + quad * 8];

    #pragma unroll
    for (int ft = 0; ft < 2; ft++) {
        int f = wave * 32 + ft * 16 + m;
        bf16x8 bg[4];
        #pragma unroll
        for (int kt = 0; kt < 4; kt++)
            bg[kt] = *(const bf16x8*)(WTg + f * 128 + kt * 32 + quad * 8);
        #pragma unroll
        for (int rt = 0; rt < 4; rt++) {
            f32x4 acc = {0,0,0,0};
            #pragma unroll
            for (int kt = 0; kt < 4; kt++)
                acc = __builtin_amdgcn_mfma_f32_16x16x32_bf16(ah[rt][kt], bg[kt], acc, 0, 0, 0);
            #pragma unroll
            for (int r = 0; r < 4; r++) {
                int n = base + rt * 16 + quad * 4 + r;
                if (n < NN)   // pre-scale by dg[n]: folds GCN coeffs into the row
                    hb[n * 128 + f] = f2b(ldsdg[rt * 16 + quad * 4 + r] * acc[r]);
            }
        }
    }
}

// ---------------------------------------------------------------------------
// Fused gather + self-loop + relu->BN->linear. One wave per destination.
// R7/R10's measured-good half-wave gather: lanes 0-31 take edge j, lanes
// 32-63 edge j+1; 4B/lane row slice; bsrc loads are per-half broadcasts (no
// cross-lane ops in the loop). Buckets CAP-strided; deg from cnt inline.
// g[d] = dg[d]*(sum_e hb[src] + hb[d]);  hb already dg[s]-scaled.
// ---------------------------------------------------------------------------
__launch_bounds__(256)
__global__ void gat_out_k(const ushort_t* __restrict__ hb, const int* __restrict__ cnt,
                          const int* __restrict__ bsrc,
                          const void* __restrict__ gcnb, const float* __restrict__ coef,
                          const int* __restrict__ mode, void* __restrict__ out) {
    int wid  = (blockIdx.x * blockDim.x + threadIdx.x) >> 6;
    int lane = threadIdx.x & 63;
    if (wid >= NN) return;
    int half = lane >> 5, sl = lane & 31;
    int c = cnt[wid]; if (c < 0) c = 0;
    int deg = (c < CAP) ? c : CAP;
    const int* brow = bsrc + wid * CAP;

    float a0 = 0.0f, a1 = 0.0f, a2 = 0.0f, a3 = 0.0f;
    int j = half;
    for (; j + 2 < deg; j += 4) {          // 2 edges per half-wave in flight
        int s0 = brow[j], s1 = brow[j + 2];
        uint2 r0 = *(const uint2*)(hb + s0 * 128 + sl * 4);
        uint2 r1 = *(const uint2*)(hb + s1 * 128 + sl * 4);
        a0 += b2f((ushort_t)(r0.x & 0xffffu)) + b2f((ushort_t)(r1.x & 0xffffu));
        a1 += b2f((ushort_t)(r0.x >> 16))     + b2f((ushort_t)(r1.x >> 16));
        a2 += b2f((ushort_t)(r0.y & 0xffffu)) + b2f((ushort_t)(r1.y & 0xffffu));
        a3 += b2f((ushort_t)(r0.y >> 16))     + b2f((ushort_t)(r1.y >> 16));
    }
    if (j < deg) {
        int s = brow[j];
        uint2 r = *(const uint2*)(hb + s * 128 + sl * 4);
        a0 += b2f((ushort_t)(r.x & 0xffffu));
        a1 += b2f((ushort_t)(r.x >> 16));
        a2 += b2f((ushort_t)(r.y & 0xffffu));
        a3 += b2f((ushort_t)(r.y >> 16));
    }
    if (half == 0) {                       // self term once (pre-combine)
        uint2 r = *(const uint2*)(hb + wid * 128 + sl * 4);
        a0 += b2f((ushort_t)(r.x & 0xffffu));
        a1 += b2f((ushort_t)(r.x >> 16));
        a2 += b2f((ushort_t)(r.y & 0xffffu));
        a3 += b2f((ushort_t)(r.y >> 16));
    }
    // combine halves (same feats in lane l and l^32)
    a0 += __shfl_xor(a0, 32); a1 += __shfl_xor(a1, 32);
    a2 += __shfl_xor(a2, 32); a3 += __shfl_xor(a3, 32);
    int mf = mode[0];
    float d = rsqrtf(1.0f + (float)c);
    int fb = sl * 4;
    float g0 = d * a0 + ldm(gcnb, fb,     mf);
    float g1 = d * a1 + ldm(gcnb, fb + 1, mf);
    float g2 = d * a2 + ldm(gcnb, fb + 2, mf);
    float g3 = d * a3 + ldm(gcnb, fb + 3, mf);
    float v = fmaxf(g0, 0.0f) * coef[512 + fb]
            + fmaxf(g1, 0.0f) * coef[512 + fb + 1]
            + fmaxf(g2, 0.0f) * coef[512 + fb + 2]
            + fmaxf(g3, 0.0f) * coef[512 + fb + 3];
    #pragma unroll
    for (int o = 32; o >= 1; o >>= 1) v += __shfl_down(v, o);   // sums both halves = 2x
    if (lane == 0) {
        float r = 0.5f * v + coef[640];
        if (mf) ((float*)out)[wid] = r;
        else    ((ushort_t*)out)[wid] = f2b(r);
    }
}

extern "C" void kernel_launch(void* const* d_in, const int* in_sizes, int n_in,
                              void* d_out, int out_size, void* d_ws, size_t ws_size,
                              hipStream_t stream) {
    if (ws_size < (size_t)WS_REQ) {   // diagnostic: finite 0.088 failure, not NaN
        fb_k<<<(out_size + 255) / 256, 256, 0, stream>>>((ushort_t*)d_out, out_size);
        return;
    }
    const void* x    = d_in[0];
    const int*  ei   = (const int*)d_in[1];
    // d_in[2] edge_weight: unused (ChebConv of zero state collapses to bias)
    const void* Wx   = d_in[3];
    const void* wc   = d_in[4];
    const void* bb   = d_in[5];
    // d_in[6] theta: unused
    const void* thb  = d_in[7];
    const void* gcnw = d_in[8];
    const void* gcnb = d_in[9];
    const void* gam  = d_in[10];
    const void* bet  = d_in[11];
    const void* mea  = d_in[12];
    const void* var  = d_in[13];
    const void* linw = d_in[14];
    const void* linb = d_in[15];

    char* ws = (char*)d_ws;
    ushort_t* hb   = (ushort_t*)(ws + OFF_HB);
    int*      bsrc = (int*)     (ws + OFF_BSRC);
    int*      cnt  = (int*)     (ws + OFF_CNT);
    ushort_t* WT   = (ushort_t*)(ws + OFF_WT);
    float*    coef = (float*)   (ws + OFF_COEF);
    int*      mode = (int*)     (ws + OFF_MODE);

    init_k<<<NP + 1, 256, 0, stream>>>((const ushort_t*)x, cnt, mode);
    prep_k<<<65, 256, 0, stream>>>(Wx, gcnw, wc, bb, thb, gam, bet, mea, var, linw, linb, mode, WT, coef);
    fill_k<<<(NE / 4 + 255) / 256, 256, 0, stream>>>(ei, cnt, bsrc);
    gates_k<<<(NN + 63) / 64, 256, 0, stream>>>(x, WT, coef, cnt, mode, hb);
    gat_out_k<<<(NN * 64 + 255) / 256, 256, 0, stream>>>(hb, cnt, bsrc, gcnb, coef, mode, d_out);
}

// Round 12
// 190.302 us; speedup vs baseline: 1.3801x; 1.0569x over previous
//
#include <hip/hip_runtime.h>
#include <hip/hip_bf16.h>

// Problem constants (reference: N, E, K, F_IN, H = 50000, 640000, 3, 128, 128)
#define NN 50000
#define NE 640000
#define NP 196          // ceil(NN/256) zero blocks
#define CAP 64          // bucket capacity; deg~Poisson(12.8), P(deg>=64)~5e-27
#define NGB 782         // gates blocks: ceil(NN/64)
#define NFB 625         // fill blocks: NE/4/256

typedef unsigned short ushort_t;
typedef unsigned int uint_t;
typedef __attribute__((ext_vector_type(8))) short bf16x8;   // 8 bf16 = 4 VGPRs
typedef __attribute__((ext_vector_type(4))) float f32x4;

__device__ __forceinline__ float b2f(ushort_t u) {
    union { uint_t u; float f; } v; v.u = ((uint_t)u) << 16; return v.f;
}
__device__ __forceinline__ ushort_t f2b(float f) {
    union { float f; uint_t u; } v; v.f = f;
    uint_t u = v.u;
    uint_t r = u + 0x7fffu + ((u >> 16) & 1u);   // round-nearest-even
    return (ushort_t)(r >> 16);
}
// fast transcendentals: v_exp + v_rcp (err ~1e-6, vs 4.9e-4 pipeline absmax)
__device__ __forceinline__ float fsig(float x)  { return __builtin_amdgcn_rcpf(1.0f + __expf(-x)); }
__device__ __forceinline__ float ftanh(float x) { return 1.0f - 2.0f * __builtin_amdgcn_rcpf(1.0f + __expf(2.0f * x)); }
// mode-aware scalar param load: mf=1 -> f32 array, mf=0 -> bf16 array
__device__ __forceinline__ float ldm(const void* p, int i, int mf) {
    return mf ? ((const float*)p)[i] : b2f(((const ushort_t*)p)[i]);
}

// ---- workspace layout (bytes), total 25.93 MB (known-good ceiling: 31.65 MB) ----
#define OFF_HB   0            // NN*128 bf16 (12,800,000)  raw h (post-gcn_w), bf16
#define OFF_BSRC 12800000     // NN*CAP i32 (12,800,000)   fixed-capacity dst buckets
#define OFF_CNT  25600000     // NN i32     (200,000)      in-degree (bucket fill count)
#define OFF_WT   25800000     // 4*16384 bf16 (131,072)    Wi^T, Wc^T, Wo^T, gcn_w^T ([f][k])
#define OFF_COEF 25931072     // 641 f32    (2,564)
#define OFF_MODE 25933640     // i32
#define WS_REQ   25933648

__global__ void fb_k(ushort_t* __restrict__ out, int n) {   // ws too small: diagnostic zeros
    int i = blockIdx.x * blockDim.x + threadIdx.x;
    if (i < n) out[i] = 0;
}

// blocks 0..NP-1: zero cnt. block NP: dtype detect (f32-as-bf16 halves show
// huge exponents ~25% >= 0xC0; real bf16 N(0,1) never does).
__global__ void init_k(const ushort_t* __restrict__ x, int* __restrict__ cnt,
                       int* __restrict__ mode) {
    __shared__ int s[256];
    int b = blockIdx.x, t = threadIdx.x;
    if (b < NP) {
        int i = b * 256 + t;
        if (i < NN) cnt[i] = 0;
    } else {
        int bad = 0;
        for (int i = t; i < 4096; i += 256) {
            int e = (x[i] >> 7) & 0xFF;
            if (e >= 0xC0) bad++;
        }
        s[t] = bad; __syncthreads();
        for (int o = 128; o >= 1; o >>= 1) { if (t < o) s[t] += s[t + o]; __syncthreads(); }
        if (t == 0) mode[0] = (s[0] > 8) ? 1 : 0;   // 1 = f32 inputs, 0 = bf16
    }
}

// blocks 0..31: transpose W_x[0],W_x[2],W_x[3],gcn_w -> bf16 [f][k].
// R12: coalesced 16B reads (8 consecutive f of one k-row), 8 fire-and-forget
// scattered stores (R11 did strided scalar READS = latency-bound).
// block 32: fold biases (cheb(0)=theta_b), peephole w_c[2], relu->BN->linear tail.
__global__ void prep_k(const void* __restrict__ Wx, const void* __restrict__ gcnw,
                       const void* __restrict__ wc, const void* __restrict__ bb,
                       const void* __restrict__ thb,
                       const void* __restrict__ gam, const void* __restrict__ bet,
                       const void* __restrict__ mea, const void* __restrict__ var,
                       const void* __restrict__ linw, const void* __restrict__ linb,
                       const int* __restrict__ mode,
                       ushort_t* __restrict__ WT, float* __restrict__ coef) {
    __shared__ float red[128];
    int b = blockIdx.x, t = threadIdx.x;
    int mf = mode[0];
    if (b < 32) {
        int gid = b * 256 + t;          // 0..8191, 2048 threads/matrix
        int m  = gid >> 11;
        int u  = gid & 2047;
        int k  = u >> 4;
        int f0 = (u & 15) << 3;
        const int srcoff[4] = { 0, 2 * 16384, 3 * 16384, 0 };
        const void* S = (m == 3) ? gcnw : Wx;
        int sbase = srcoff[m] + k * 128 + f0;
        ushort_t vals[8];
        if (mf == 0) {
            bf16x8 v = *(const bf16x8*)((const ushort_t*)S + sbase);
            #pragma unroll
            for (int i = 0; i < 8; i++) vals[i] = (ushort_t)v[i];
        } else {
            const float* Sf = (const float*)S + sbase;
            #pragma unroll
            for (int i = 0; i < 8; i++) vals[i] = f2b(Sf[i]);
        }
        ushort_t* D = WT + m * 16384 + k;
        #pragma unroll
        for (int i = 0; i < 8; i++) D[(f0 + i) * 128] = vals[i];
    } else {
        if (t < 128) {
            float rs = rsqrtf(ldm(var, t, mf) + 1e-5f);
            float ga = ldm(gam, t, mf);
            float lw = ldm(linw, t, mf);
            coef[t]       = ldm(thb, t, mf)           + ldm(bb, t, mf);            // bias_i
            coef[128 + t] = ldm(thb, 2 * 128 + t, mf) + ldm(bb, 2 * 128 + t, mf);  // bias_c
            coef[256 + t] = ldm(thb, 3 * 128 + t, mf) + ldm(bb, 3 * 128 + t, mf);  // bias_o
            coef[384 + t] = ldm(wc, 2 * 128 + t, mf);                              // w_c[2]
            coef[512 + t] = ga * rs * lw;                                          // s[f]
            red[t] = (ldm(bet, t, mf) - ldm(mea, t, mf) * ga * rs) * lw;
        }
        __syncthreads();
        for (int off = 64; off >= 1; off >>= 1) {
            if (t < off && t < 128) red[t] += red[t + off];
            __syncthreads();
        }
        if (t == 0) coef[640] = red[0] + ldm(linb, 0, mf);                         // C
    }
}

// ---------------------------------------------------------------------------
// R12 fused kernel: gates GEMM blocks + fill (bucket) blocks interleaved 5:4
// so fill's contended-atomic latency (measured floor ~45us standalone, R10/R11)
// overlaps gates' MFMA/VALU work. Independence: gates no longer pre-scales by
// dg (stores RAW h); gat_out applies dg[s] from L2-resident cnt.
//   gates: one block = 4 waves = 64 nodes; wave w owns feature cols
//   [32w,32w+32) for all rows (B-frags load once, reuse over 4 row tiles).
//   MFMA f32_16x16x32_bf16 layouts (HW-verified):
//   A: a[j]=A[m=lane&15][k=(lane>>4)*8+j];  B: b[j]=B[k=(lane>>4)*8+j][n=lane&15]
//   D: reg r -> row (lane>>4)*4+r, col lane&15
//   fill: 4 edges/thread via int4; slot = atomicAdd(cnt[d]) (returning).
// ---------------------------------------------------------------------------
__launch_bounds__(256)
__global__ void gafi_k(const void* __restrict__ x, const ushort_t* __restrict__ WT,
                       const float* __restrict__ coef, const int* __restrict__ mode,
                       ushort_t* __restrict__ hb,
                       const int* __restrict__ ei, int* __restrict__ cnt,
                       int* __restrict__ bsrc) {
    __shared__ ushort_t tile[64 * 136];   // +8 pad: row stride 272B (gates path only)
    int per = blockIdx.x / 9, rem = blockIdx.x % 9;
    int t = threadIdx.x;

    if (rem >= 5) {                       // ---- fill path ----
        int fb = per * 4 + (rem - 5);
        if (fb >= NFB) return;
        int tid = fb * 256 + t;           // < NE/4 by construction
        int4 s4 = ((const int4*)ei)[tid];
        int4 d4 = ((const int4*)(ei + NE))[tid];
        int p0 = atomicAdd(&cnt[d4.x], 1);
        int p1 = atomicAdd(&cnt[d4.y], 1);
        int p2 = atomicAdd(&cnt[d4.z], 1);
        int p3 = atomicAdd(&cnt[d4.w], 1);
        if (p0 < CAP) bsrc[d4.x * CAP + p0] = s4.x;
        if (p1 < CAP) bsrc[d4.y * CAP + p1] = s4.y;
        if (p2 < CAP) bsrc[d4.z * CAP + p2] = s4.z;
        if (p3 < CAP) bsrc[d4.w * CAP + p3] = s4.w;
        return;
    }

    // ---- gates path ----
    int gb = per * 5 + rem;
    if (gb >= NGB) return;
    int base = gb * 64;
    int mf = mode[0];

    for (int i = 0; i < 4; i++) {
        int idx = (i * 256 + t) * 8;
        int row = idx >> 7, col = idx & 127;
        int n = base + row;
        bf16x8 v;
        if (n >= NN) {
            v = (bf16x8)0;
        } else if (mf == 0) {
            v = *(const bf16x8*)((const ushort_t*)x + n * 128 + col);
        } else {
            const float* xf = (const float*)x + n * 128 + col;
            float4 lo = *(const float4*)xf;
            float4 hi = *(const float4*)(xf + 4);
            v[0] = (short)f2b(lo.x); v[1] = (short)f2b(lo.y);
            v[2] = (short)f2b(lo.z); v[3] = (short)f2b(lo.w);
            v[4] = (short)f2b(hi.x); v[5] = (short)f2b(hi.y);
            v[6] = (short)f2b(hi.z); v[7] = (short)f2b(hi.w);
        }
        *(bf16x8*)&tile[row * 136 + col] = v;
    }
    __syncthreads();

    int lane = t & 63, wave = t >> 6;
    int m = lane & 15, quad = lane >> 4;

    bf16x8 a[4][4];
    #pragma unroll
    for (int rt = 0; rt < 4; rt++)
        #pragma unroll
        for (int kt = 0; kt < 4; kt++)
            a[rt][kt] = *(const bf16x8*)&tile[(rt * 16 + m) * 136 + kt * 32 + quad * 8];
    __syncthreads();   // all x reads done before Hs overwrites tile

    const ushort_t* WTi = WT;
    const ushort_t* WTc = WT + 16384;
    const ushort_t* WTo = WT + 2 * 16384;

    #pragma unroll
    for (int ft = 0; ft < 2; ft++) {
        int f = wave * 32 + ft * 16 + m;
        bf16x8 bi[4], bc[4], bo[4];
        #pragma unroll
        for (int kt = 0; kt < 4; kt++) {
            int off = f * 128 + kt * 32 + quad * 8;
            bi[kt] = *(const bf16x8*)(WTi + off);
            bc[kt] = *(const bf16x8*)(WTc + off);
            bo[kt] = *(const bf16x8*)(WTo + off);
        }
        float bi_f = coef[f], bc_f = coef[128 + f], bo_f = coef[256 + f], w2 = coef[384 + f];
        #pragma unroll
        for (int rt = 0; rt < 4; rt++) {
            f32x4 ai = {0,0,0,0}, ac = {0,0,0,0}, ao = {0,0,0,0};
            #pragma unroll
            for (int kt = 0; kt < 4; kt++) {
                ai = __builtin_amdgcn_mfma_f32_16x16x32_bf16(a[rt][kt], bi[kt], ai, 0, 0, 0);
                ac = __builtin_amdgcn_mfma_f32_16x16x32_bf16(a[rt][kt], bc[kt], ac, 0, 0, 0);
                ao = __builtin_amdgcn_mfma_f32_16x16x32_bf16(a[rt][kt], bo[kt], ao, 0, 0, 0);
            }
            #pragma unroll
            for (int r = 0; r < 4; r++) {
                float I  = fsig(ai[r] + bi_f);
                float T  = ftanh(ac[r] + bc_f);
                float Cs = I * T;                       // F*C_prev = 0
                float O  = fsig(ao[r] + w2 * Cs + bo_f);
                float Hs = O * ftanh(Cs);
                tile[(rt * 16 + quad * 4 + r) * 136 + f] = f2b(Hs);
            }
        }
    }
    __syncthreads();   // Hs tile complete (col-partitioned across waves)

    const ushort_t* WTg = WT + 3 * 16384;
    bf16x8 ah[4][4];
    #pragma unroll
    for (int rt = 0; rt < 4; rt++)
        #pragma unroll
        for (int kt = 0; kt < 4; kt++)
            ah[rt][kt] = *(const bf16x8*)&tile[(rt * 16 + m) * 136 + kt * 32 + quad * 8];

    #pragma unroll
    for (int ft = 0; ft < 2; ft++) {
        int f = wave * 32 + ft * 16 + m;
        bf16x8 bg[4];
        #pragma unroll
        for (int kt = 0; kt < 4; kt++)
            bg[kt] = *(const bf16x8*)(WTg + f * 128 + kt * 32 + quad * 8);
        #pragma unroll
        for (int rt = 0; rt < 4; rt++) {
            f32x4 acc = {0,0,0,0};
            #pragma unroll
            for (int kt = 0; kt < 4; kt++)
                acc = __builtin_amdgcn_mfma_f32_16x16x32_bf16(ah[rt][kt], bg[kt], acc, 0, 0, 0);
            #pragma unroll
            for (int r = 0; r < 4; r++) {
                int n = base + rt * 16 + quad * 4 + r;
                if (n < NN) hb[n * 128 + f] = f2b(acc[r]);   // RAW h (no dg pre-scale)
            }
        }
    }
}

// ---------------------------------------------------------------------------
// Fused gather + self-loop + relu->BN->linear. One wave per destination.
// Half-wave per edge (R7/R10 measured-good); R12 adds: (a) software-pipelined
// index prefetch (brow[j+4/6] masked in-bounds, value used only when valid)
// so idx->row latency leaves the critical path; (b) per-edge dg[s] from
// L2-resident cnt (broadcast load across the half) since hb is now raw h.
// g[d] = dg[d]*(sum_e dg[s]*h[s] + dg[d]*h[d])
// ---------------------------------------------------------------------------
__launch_bounds__(256)
__global__ void gat_out_k(const ushort_t* __restrict__ hb, const int* __restrict__ cnt,
                          const int* __restrict__ bsrc,
                          const void* __restrict__ gcnb, const float* __restrict__ coef,
                          const int* __restrict__ mode, void* __restrict__ out) {
    int wid  = (blockIdx.x * blockDim.x + threadIdx.x) >> 6;
    int lane = threadIdx.x & 63;
    if (wid >= NN) return;
    int half = lane >> 5, sl = lane & 31;
    int c = cnt[wid]; if (c < 0) c = 0;
    int deg = (c < CAP) ? c : CAP;
    const int* brow = bsrc + wid * CAP;

    float a0 = 0.0f, a1 = 0.0f, a2 = 0.0f, a3 = 0.0f;
    int s0 = brow[half];                   // in-bounds slots; value valid iff idx < deg
    int s1 = brow[half + 2];
    for (int j = half; j < deg; j += 4) {
        int sn0 = brow[(j + 4) & (CAP - 1)];   // speculative prefetch, in-bounds
        int sn1 = brow[(j + 6) & (CAP - 1)];
        {   // edge j: valid (loop condition)
            int cs = cnt[s0]; if (cs < 0) cs = 0;
            uint2 r = *(const uint2*)(hb + s0 * 128 + sl * 4);
            float w = rsqrtf(1.0f + (float)cs);
            a0 += w * b2f((ushort_t)(r.x & 0xffffu));
            a1 += w * b2f((ushort_t)(r.x >> 16));
            a2 += w * b2f((ushort_t)(r.y & 0xffffu));
            a3 += w * b2f((ushort_t)(r.y >> 16));
        }
        if (j + 2 < deg) {
            int cs = cnt[s1]; if (cs < 0) cs = 0;
            uint2 r = *(const uint2*)(hb + s1 * 128 + sl * 4);
            float w = rsqrtf(1.0f + (float)cs);
            a0 += w * b2f((ushort_t)(r.x & 0xffffu));
            a1 += w * b2f((ushort_t)(r.x >> 16));
            a2 += w * b2f((ushort_t)(r.y & 0xffffu));
            a3 += w * b2f((ushort_t)(r.y >> 16));
        }
        s0 = sn0; s1 = sn1;
    }
    float d = rsqrtf(1.0f + (float)c);
    if (half == 0) {                       // self term once (weight dg[d], pre-combine)
        uint2 r = *(const uint2*)(hb + wid * 128 + sl * 4);
        a0 += d * b2f((ushort_t)(r.x & 0xffffu));
        a1 += d * b2f((ushort_t)(r.x >> 16));
        a2 += d * b2f((ushort_t)(r.y & 0xffffu));
        a3 += d * b2f((ushort_t)(r.y >> 16));
    }
    // combine halves (same feats in lane l and l^32)
    a0 += __shfl_xor(a0, 32); a1 += __shfl_xor(a1, 32);
    a2 += __shfl_xor(a2, 32); a3 += __shfl_xor(a3, 32);
    int mf = mode[0];
    int fb = sl * 4;
    float g0 = d * a0 + ldm(gcnb, fb,     mf);
    float g1 = d * a1 + ldm(gcnb, fb + 1, mf);
    float g2 = d * a2 + ldm(gcnb, fb + 2, mf);
    float g3 = d * a3 + ldm(gcnb, fb + 3, mf);
    float v = fmaxf(g0, 0.0f) * coef[512 + fb]
            + fmaxf(g1, 0.0f) * coef[512 + fb + 1]
            + fmaxf(g2, 0.0f) * coef[512 + fb + 2]
            + fmaxf(g3, 0.0f) * coef[512 + fb + 3];
    #pragma unroll
    for (int o = 32; o >= 1; o >>= 1) v += __shfl_down(v, o);   // sums both halves = 2x
    if (lane == 0) {
        float r = 0.5f * v + coef[640];
        if (mf) ((float*)out)[wid] = r;
        else    ((ushort_t*)out)[wid] = f2b(r);
    }
}

extern "C" void kernel_launch(void* const* d_in, const int* in_sizes, int n_in,
                              void* d_out, int out_size, void* d_ws, size_t ws_size,
                              hipStream_t stream) {
    if (ws_size < (size_t)WS_REQ) {   // diagnostic: finite 0.088 failure, not NaN
        fb_k<<<(out_size + 255) / 256, 256, 0, stream>>>((ushort_t*)d_out, out_size);
        return;
    }
    const void* x    = d_in[0];
    const int*  ei   = (const int*)d_in[1];
    // d_in[2] edge_weight: unused (ChebConv of zero state collapses to bias)
    const void* Wx   = d_in[3];
    const void* wc   = d_in[4];
    const void* bb   = d_in[5];
    // d_in[6] theta: unused
    const void* thb  = d_in[7];
    const void* gcnw = d_in[8];
    const void* gcnb = d_in[9];
    const void* gam  = d_in[10];
    const void* bet  = d_in[11];
    const void* mea  = d_in[12];
    const void* var  = d_in[13];
    const void* linw = d_in[14];
    const void* linb = d_in[15];

    char* ws = (char*)d_ws;
    ushort_t* hb   = (ushort_t*)(ws + OFF_HB);
    int*      bsrc = (int*)     (ws + OFF_BSRC);
    int*      cnt  = (int*)     (ws + OFF_CNT);
    ushort_t* WT   = (ushort_t*)(ws + OFF_WT);
    float*    coef = (float*)   (ws + OFF_COEF);
    int*      mode = (int*)     (ws + OFF_MODE);

    init_k<<<NP + 1, 256, 0, stream>>>((const ushort_t*)x, cnt, mode);
    prep_k<<<33, 256, 0, stream>>>(Wx, gcnw, wc, bb, thb, gam, bet, mea, var, linw, linb, mode, WT, coef);
    gafi_k<<<157 * 9, 256, 0, stream>>>(x, WT, coef, mode, hb, ei, cnt, bsrc);
    gat_out_k<<<(NN * 64 + 255) / 256, 256, 0, stream>>>(hb, cnt, bsrc, gcnb, coef, mode, d_out);
}